// Round 6
// baseline (2106.248 us; speedup 1.0000x reference)
//
#include <hip/hip_runtime.h>
#include <hip/hip_fp16.h>

#define N 8192
#define ITERS 50
#define ROWS 8   // rows per gemv block

typedef unsigned int uint32;

// ws layout: [fp16 plane 128MiB][bufA N][bufB N][nsq ITERS+1]
// fp16 plane: row-major __half, RTNE from fp32. Hot loop: uint4 loads
// (8 halfs/lane, 64 lanes = 1KB contiguous per instruction).

__global__ void pi_init_kernel(float* __restrict__ bufA, float* __restrict__ nsq) {
    int i = blockIdx.x * blockDim.x + threadIdx.x;
    if (i < N) bufA[i] = 1.0f;
    if (i <= ITERS) nsq[i] = (i == 0) ? 1.0f : 0.0f;
}

// epilogue for ROWS-per-block gemv kernels: per-row wave reduce -> LDS ->
// write vout, accumulate sum(vout^2) into nsq_next
__device__ __forceinline__ void pi_epilogue(float (&acc)[ROWS], int t, int row0,
                                            float s, float* __restrict__ vout,
                                            float* __restrict__ nsq_next) {
#pragma unroll
    for (int r = 0; r < ROWS; ++r) {
        float a = acc[r];
        for (int off = 32; off > 0; off >>= 1) a += __shfl_down(a, off, 64);
        acc[r] = a;
    }
    __shared__ float part[4][ROWS];
    const int wave = t >> 6, lane = t & 63;
    if (lane == 0) {
#pragma unroll
        for (int r = 0; r < ROWS; ++r) part[wave][r] = acc[r];
    }
    __syncthreads();
    float sq = 0.0f;
    if (t < ROWS) {
        const float sum = part[0][t] + part[1][t] + part[2][t] + part[3][t];
        const float y = sum * s;
        vout[row0 + t] = y;
        sq = y * y;
    }
    if (wave == 0) {
        for (int off = 32; off > 0; off >>= 1) sq += __shfl_down(sq, off, 64);
        if (lane == 0) atomicAdd(nsq_next, sq);
    }
}

// fp32 GEMV (fallback for small ws)
__global__ __launch_bounds__(256) void pi_gemv_kernel(
        const float4* __restrict__ M4,
        const float4* __restrict__ vin4,
        float* __restrict__ vout,
        const float* __restrict__ nsq_prev,
        float* __restrict__ nsq_next) {
    const int t = threadIdx.x;
    const int row0 = blockIdx.x * ROWS;
    const float s = rsqrtf(*nsq_prev);
    constexpr int NV = N / 4;
    constexpr int CHUNKS = NV / 256;
    float acc[ROWS];
#pragma unroll
    for (int r = 0; r < ROWS; ++r) acc[r] = 0.0f;
    for (int c = 0; c < CHUNKS; ++c) {
        const int idx = c * 256 + t;
        const float4 vv = vin4[idx];
#pragma unroll
        for (int r = 0; r < ROWS; ++r) {
            const float4 m = M4[(size_t)(row0 + r) * NV + idx];
            acc[r] += m.x * vv.x + m.y * vv.y + m.z * vv.z + m.w * vv.w;
        }
    }
    pi_epilogue(acc, t, row0, s, vout, nsq_next);
}

__device__ __forceinline__ uint32 pack2h(float x, float y) {
    __half2 p = __float22half2_rn(make_float2(x, y));
    return *reinterpret_cast<uint32*>(&p);
}

// iter 1: fp32 GEMV fused with fp16 conversion. One row per block.
__global__ __launch_bounds__(256) void pi_convert_kernel(
        const float4* __restrict__ M4,
        const float4* __restrict__ vin4,
        float* __restrict__ vout,
        const float* __restrict__ nsq_prev,
        float* __restrict__ nsq_next,
        uint4* __restrict__ h4) {
    const int row = blockIdx.x;
    const int t = threadIdx.x, w = t >> 6, l = t & 63;
    const float s = rsqrtf(*nsq_prev);
    const size_t rf = (size_t)row * (N / 4);   // float4 row base
    const size_t rh = (size_t)row * (N / 8);   // uint4  row base (1024)
    float a = 0.0f;
#pragma unroll
    for (int half = 0; half < 2; ++half) {
        const int tile = w + 4 * half;         // 0..7, 1024 elems each
        float4 m[4];
#pragma unroll
        for (int j = 0; j < 4; ++j) m[j] = M4[rf + tile * 256 + 4 * l + j];
#pragma unroll
        for (int j = 0; j < 4; ++j) {
            const float4 vv = vin4[tile * 256 + 4 * l + j];
            a += m[j].x * vv.x + m[j].y * vv.y + m[j].z * vv.z + m[j].w * vv.w;
        }
        uint4 o0, o1;
        o0.x = pack2h(m[0].x, m[0].y);
        o0.y = pack2h(m[0].z, m[0].w);
        o0.z = pack2h(m[1].x, m[1].y);
        o0.w = pack2h(m[1].z, m[1].w);
        o1.x = pack2h(m[2].x, m[2].y);
        o1.y = pack2h(m[2].z, m[2].w);
        o1.z = pack2h(m[3].x, m[3].y);
        o1.w = pack2h(m[3].z, m[3].w);
        h4[rh + tile * 128 + 2 * l]     = o0;
        h4[rh + tile * 128 + 2 * l + 1] = o1;
    }
    for (int off = 32; off > 0; off >>= 1) a += __shfl_down(a, off, 64);
    __shared__ float part[4];
    if (l == 0) part[w] = a;
    __syncthreads();
    if (t == 0) {
        const float sum = part[0] + part[1] + part[2] + part[3];
        const float y = sum * s;
        vout[row] = y;
        atomicAdd(nsq_next, y * y);
    }
}

__device__ __forceinline__ float2 h2f(uint32 u) {
    __half2 h = *reinterpret_cast<__half2*>(&u);
    return __half22float2(h);
}

// fp16 GEMV: all M loads 16B uint4 (1KB/wave contiguous). VGPR capped via
// launch_bounds(256,4) -> guaranteed 4 blocks/CU (16 waves/CU).
__global__ __launch_bounds__(256, 4) void pi_gemv2h_kernel(
        const uint4* __restrict__ h4,    // row stride N/8 = 1024 uint4
        const float4* __restrict__ vin4,
        float* __restrict__ vout,
        const float* __restrict__ nsq_prev,
        float* __restrict__ nsq_next) {
    const int t = threadIdx.x;
    const int row0 = blockIdx.x * ROWS;
    const float s = rsqrtf(*nsq_prev);

    // preload this thread's v slices once: chunk c covers elems 8*(c*256+t)..+7
    float4 va[4], vb[4];
#pragma unroll
    for (int c = 0; c < 4; ++c) {
        const int idx = c * 256 + t;
        va[c] = vin4[2 * idx];
        vb[c] = vin4[2 * idx + 1];
    }

    float acc[ROWS];
#pragma unroll
    for (int r = 0; r < ROWS; ++r) acc[r] = 0.0f;
#pragma unroll
    for (int c = 0; c < 4; ++c) {
        const int idx = c * 256 + t;           // uint4 index in row, 0..1023
#pragma unroll
        for (int r = 0; r < ROWS; ++r) {
            const uint4 h = h4[(size_t)(row0 + r) * 1024 + idx];
            const float2 f0 = h2f(h.x);
            const float2 f1 = h2f(h.y);
            const float2 f2 = h2f(h.z);
            const float2 f3 = h2f(h.w);
            acc[r] += f0.x * va[c].x + f0.y * va[c].y + f1.x * va[c].z + f1.y * va[c].w +
                      f2.x * vb[c].x + f2.y * vb[c].y + f3.x * vb[c].z + f3.y * vb[c].w;
        }
    }
    pi_epilogue(acc, t, row0, s, vout, nsq_next);
}

__global__ void pi_scale_kernel(const float* __restrict__ vin,
                                const float* __restrict__ nsq,
                                float* __restrict__ out) {
    int i = blockIdx.x * blockDim.x + threadIdx.x;
    const float s = rsqrtf(*nsq);
    if (i < N) out[i] = vin[i] * s;
}

extern "C" void kernel_launch(void* const* d_in, const int* in_sizes, int n_in,
                              void* d_out, int out_size, void* d_ws, size_t ws_size,
                              hipStream_t stream) {
    const float* M = (const float*)d_in[0];
    float* out = (float*)d_out;

    const size_t H_BYTES = (size_t)N * N * 2;   // 128 MiB fp16 plane
    const size_t VEC_BYTES = (size_t)(2 * N + ITERS + 1) * sizeof(float);
    const bool use2 = (ws_size >= H_BYTES + VEC_BYTES);

    char* ws = (char*)d_ws;
    float* bufA;
    float* bufB;
    float* nsq;
    uint4* h4 = nullptr;
    if (use2) {
        h4   = (uint4*)ws;
        bufA = (float*)(ws + H_BYTES);
        bufB = bufA + N;
        nsq  = bufB + N;
    } else {
        bufA = (float*)ws;
        bufB = bufA + N;
        nsq  = bufB + N;
    }

    pi_init_kernel<<<(N + 255) / 256, 256, 0, stream>>>(bufA, nsq);

    const float4* M4 = (const float4*)M;
    if (use2) {
        pi_convert_kernel<<<N, 256, 0, stream>>>(
            M4, (const float4*)bufA, bufB, nsq, nsq + 1, h4);
        for (int k = 2; k <= ITERS; ++k) {
            const float* vin = (k & 1) ? bufA : bufB;
            float* vout      = (k & 1) ? bufB : bufA;
            pi_gemv2h_kernel<<<N / ROWS, 256, 0, stream>>>(
                h4, (const float4*)vin, vout, nsq + (k - 1), nsq + k);
        }
    } else {
        for (int k = 1; k <= ITERS; ++k) {
            const float* vin = (k & 1) ? bufA : bufB;
            float* vout      = (k & 1) ? bufB : bufA;
            pi_gemv_kernel<<<N / ROWS, 256, 0, stream>>>(
                M4, (const float4*)vin, vout, nsq + (k - 1), nsq + k);
        }
    }
    pi_scale_kernel<<<(N + 255) / 256, 256, 0, stream>>>(bufA, nsq + ITERS, out);
}

// Round 7
// 1536.084 us; speedup vs baseline: 1.3712x; 1.3712x over previous
//
#include <hip/hip_runtime.h>
#include <hip/hip_fp16.h>

#define N 8192
#define ITERS 50
#define ROWS 8   // rows per gemv block

typedef unsigned int uint32;

#define AS1 __attribute__((address_space(1)))
#define AS3 __attribute__((address_space(3)))

// async global->LDS, 16B per lane: lane l writes ldsbase + l*16
__device__ __forceinline__ void gload_lds16(const void* g, void* l) {
    __builtin_amdgcn_global_load_lds((const AS1 void*)g, (AS3 void*)l, 16, 0, 0);
}

// ws layout: [fp16 plane 128MiB][bufA N][bufB N][nsq ITERS+1]

__global__ void pi_init_kernel(float* __restrict__ bufA, float* __restrict__ nsq) {
    int i = blockIdx.x * blockDim.x + threadIdx.x;
    if (i < N) bufA[i] = 1.0f;
    if (i <= ITERS) nsq[i] = (i == 0) ? 1.0f : 0.0f;
}

// epilogue: per-row wave reduce -> LDS -> write vout, accumulate sum(y^2)
__device__ __forceinline__ void pi_epilogue(float (&acc)[ROWS], int t, int row0,
                                            float s, float* __restrict__ vout,
                                            float* __restrict__ nsq_next) {
#pragma unroll
    for (int r = 0; r < ROWS; ++r) {
        float a = acc[r];
        for (int off = 32; off > 0; off >>= 1) a += __shfl_down(a, off, 64);
        acc[r] = a;
    }
    __shared__ float part[4][ROWS];
    const int wave = t >> 6, lane = t & 63;
    if (lane == 0) {
#pragma unroll
        for (int r = 0; r < ROWS; ++r) part[wave][r] = acc[r];
    }
    __syncthreads();
    float sq = 0.0f;
    if (t < ROWS) {
        const float sum = part[0][t] + part[1][t] + part[2][t] + part[3][t];
        const float y = sum * s;
        vout[row0 + t] = y;
        sq = y * y;
    }
    if (wave == 0) {
        for (int off = 32; off > 0; off >>= 1) sq += __shfl_down(sq, off, 64);
        if (lane == 0) atomicAdd(nsq_next, sq);
    }
}

// fp32 GEMV (fallback for small ws)
__global__ __launch_bounds__(256) void pi_gemv_kernel(
        const float4* __restrict__ M4,
        const float4* __restrict__ vin4,
        float* __restrict__ vout,
        const float* __restrict__ nsq_prev,
        float* __restrict__ nsq_next) {
    const int t = threadIdx.x;
    const int row0 = blockIdx.x * ROWS;
    const float s = rsqrtf(*nsq_prev);
    constexpr int NV = N / 4;
    constexpr int CHUNKS = NV / 256;
    float acc[ROWS];
#pragma unroll
    for (int r = 0; r < ROWS; ++r) acc[r] = 0.0f;
    for (int c = 0; c < CHUNKS; ++c) {
        const int idx = c * 256 + t;
        const float4 vv = vin4[idx];
#pragma unroll
        for (int r = 0; r < ROWS; ++r) {
            const float4 m = M4[(size_t)(row0 + r) * NV + idx];
            acc[r] += m.x * vv.x + m.y * vv.y + m.z * vv.z + m.w * vv.w;
        }
    }
    pi_epilogue(acc, t, row0, s, vout, nsq_next);
}

__device__ __forceinline__ uint32 pack2h(float x, float y) {
    __half2 p = __float22half2_rn(make_float2(x, y));
    return *reinterpret_cast<uint32*>(&p);
}

// iter 1: fp32 GEMV fused with fp16 conversion. One row per block.
__global__ __launch_bounds__(256) void pi_convert_kernel(
        const float4* __restrict__ M4,
        const float4* __restrict__ vin4,
        float* __restrict__ vout,
        const float* __restrict__ nsq_prev,
        float* __restrict__ nsq_next,
        uint4* __restrict__ h4) {
    const int row = blockIdx.x;
    const int t = threadIdx.x, w = t >> 6, l = t & 63;
    const float s = rsqrtf(*nsq_prev);
    const size_t rf = (size_t)row * (N / 4);
    const size_t rh = (size_t)row * (N / 8);
    float a = 0.0f;
#pragma unroll
    for (int half = 0; half < 2; ++half) {
        const int tile = w + 4 * half;
        float4 m[4];
#pragma unroll
        for (int j = 0; j < 4; ++j) m[j] = M4[rf + tile * 256 + 4 * l + j];
#pragma unroll
        for (int j = 0; j < 4; ++j) {
            const float4 vv = vin4[tile * 256 + 4 * l + j];
            a += m[j].x * vv.x + m[j].y * vv.y + m[j].z * vv.z + m[j].w * vv.w;
        }
        uint4 o0, o1;
        o0.x = pack2h(m[0].x, m[0].y);
        o0.y = pack2h(m[0].z, m[0].w);
        o0.z = pack2h(m[1].x, m[1].y);
        o0.w = pack2h(m[1].z, m[1].w);
        o1.x = pack2h(m[2].x, m[2].y);
        o1.y = pack2h(m[2].z, m[2].w);
        o1.z = pack2h(m[3].x, m[3].y);
        o1.w = pack2h(m[3].z, m[3].w);
        h4[rh + tile * 128 + 2 * l]     = o0;
        h4[rh + tile * 128 + 2 * l + 1] = o1;
    }
    for (int off = 32; off > 0; off >>= 1) a += __shfl_down(a, off, 64);
    __shared__ float part[4];
    if (l == 0) part[w] = a;
    __syncthreads();
    if (t == 0) {
        const float sum = part[0] + part[1] + part[2] + part[3];
        const float y = sum * s;
        vout[row] = y;
        atomicAdd(nsq_next, y * y);
    }
}

__device__ __forceinline__ float2 h2f(uint32 u) {
    __half2 h = *reinterpret_cast<__half2*>(&u);
    return __half22float2(h);
}

// fp16 GEMV with async LDS staging: 4 chunks/row, double-buffered 32KB LDS,
// counted vmcnt (never 0 mid-loop). MLP lives in the DMA queue, not VGPRs.
__global__ __launch_bounds__(256) void pi_gemv2h_lds_kernel(
        const __half* __restrict__ hplane,   // row-major N x N
        const float4* __restrict__ vin4,
        float* __restrict__ vout,
        const float* __restrict__ nsq_prev,
        float* __restrict__ nsq_next) {
    // chunk = 256 uint4 (2048 halfs, 4KB) per row; buffer = 8 rows x 4KB = 32KB
    __shared__ uint4 sbuf[2][ROWS][256];
    const int t = threadIdx.x, w = t >> 6, l = t & 63;
    const int row0 = blockIdx.x * ROWS;
    const float s = rsqrtf(*nsq_prev);

    // preload vin: chunk c, uint4 t -> elems 8*(c*256+t)..+7
    float4 va[4], vb[4];
#pragma unroll
    for (int c = 0; c < 4; ++c) {
        va[c] = vin4[2 * (c * 256 + t)];
        vb[c] = vin4[2 * (c * 256 + t) + 1];
    }
    // drain ALL compiler VMEM before the counted-staging region
    asm volatile("s_waitcnt vmcnt(0)" ::: "memory");

    const __half* rowbase = hplane + (size_t)row0 * N;
    float acc[ROWS];
#pragma unroll
    for (int r = 0; r < ROWS; ++r) acc[r] = 0.0f;

    // wave w stages rows 2w, 2w+1 (4 x 1KB quarters each) = 8 loads/wave/chunk
#define STAGE(c, b)                                                           \
    {                                                                         \
        _Pragma("unroll")                                                     \
        for (int rr = 0; rr < 2; ++rr) {                                      \
            const int r = 2 * w + rr;                                         \
            const char* gb =                                                  \
                (const char*)(rowbase + (size_t)r * N + (c) * 2048) + l * 16; \
            _Pragma("unroll")                                                 \
            for (int q = 0; q < 4; ++q) {                                     \
                gload_lds16(gb + q * 1024, (void*)&sbuf[b][r][q * 64]);       \
            }                                                                 \
        }                                                                     \
    }

#define COMPUTE(c, b)                                                         \
    {                                                                         \
        _Pragma("unroll")                                                     \
        for (int r = 0; r < ROWS; ++r) {                                      \
            const uint4 h = sbuf[b][r][t];                                    \
            const float2 f0 = h2f(h.x);                                       \
            const float2 f1 = h2f(h.y);                                       \
            const float2 f2 = h2f(h.z);                                       \
            const float2 f3 = h2f(h.w);                                       \
            acc[r] += f0.x * va[c].x + f0.y * va[c].y + f1.x * va[c].z +      \
                      f1.y * va[c].w + f2.x * vb[c].x + f2.y * vb[c].y +      \
                      f3.x * vb[c].z + f3.y * vb[c].w;                        \
        }                                                                     \
    }

#define WAITV(n) asm volatile("s_waitcnt vmcnt(" #n ")" ::: "memory")
#define WAITL    asm volatile("s_waitcnt lgkmcnt(0)" ::: "memory")
#define BAR      __builtin_amdgcn_s_barrier(); asm volatile("" ::: "memory")

    STAGE(0, 0)                    // 8 outstanding
    STAGE(1, 1)                    // 16
    WAITV(8); BAR;                 // c0 landed (all waves) ; c1 in flight
    COMPUTE(0, 0)
    WAITL; BAR;                    // all waves done reading buf0
    STAGE(2, 0)                    // c1(8) + c2(8) = 16
    WAITV(8); BAR;                 // c1 landed ; c2 in flight
    COMPUTE(1, 1)
    WAITL; BAR;                    // all waves done reading buf1
    STAGE(3, 1)                    // c2(8) + c3(8) = 16
    WAITV(8); BAR;                 // c2 landed ; c3 in flight
    COMPUTE(2, 0)
    WAITV(0); WAITL; BAR;          // c3 landed
    COMPUTE(3, 1)

#undef STAGE
#undef COMPUTE
#undef WAITV
#undef WAITL
#undef BAR

    pi_epilogue(acc, t, row0, s, vout, nsq_next);
}

__global__ void pi_scale_kernel(const float* __restrict__ vin,
                                const float* __restrict__ nsq,
                                float* __restrict__ out) {
    int i = blockIdx.x * blockDim.x + threadIdx.x;
    const float s = rsqrtf(*nsq);
    if (i < N) out[i] = vin[i] * s;
}

extern "C" void kernel_launch(void* const* d_in, const int* in_sizes, int n_in,
                              void* d_out, int out_size, void* d_ws, size_t ws_size,
                              hipStream_t stream) {
    const float* M = (const float*)d_in[0];
    float* out = (float*)d_out;

    const size_t H_BYTES = (size_t)N * N * 2;   // 128 MiB fp16 plane
    const size_t VEC_BYTES = (size_t)(2 * N + ITERS + 1) * sizeof(float);
    const bool use2 = (ws_size >= H_BYTES + VEC_BYTES);

    char* ws = (char*)d_ws;
    float* bufA;
    float* bufB;
    float* nsq;
    uint4* h4 = nullptr;
    if (use2) {
        h4   = (uint4*)ws;
        bufA = (float*)(ws + H_BYTES);
        bufB = bufA + N;
        nsq  = bufB + N;
    } else {
        bufA = (float*)ws;
        bufB = bufA + N;
        nsq  = bufB + N;
    }

    pi_init_kernel<<<(N + 255) / 256, 256, 0, stream>>>(bufA, nsq);

    const float4* M4 = (const float4*)M;
    if (use2) {
        pi_convert_kernel<<<N, 256, 0, stream>>>(
            M4, (const float4*)bufA, bufB, nsq, nsq + 1, h4);
        for (int k = 2; k <= ITERS; ++k) {
            const float* vin = (k & 1) ? bufA : bufB;
            float* vout      = (k & 1) ? bufB : bufA;
            pi_gemv2h_lds_kernel<<<N / ROWS, 256, 0, stream>>>(
                (const __half*)h4, (const float4*)vin, vout,
                nsq + (k - 1), nsq + k);
        }
    } else {
        for (int k = 1; k <= ITERS; ++k) {
            const float* vin = (k & 1) ? bufA : bufB;
            float* vout      = (k & 1) ? bufB : bufA;
            pi_gemv_kernel<<<N / ROWS, 256, 0, stream>>>(
                M4, (const float4*)vin, vout, nsq + (k - 1), nsq + k);
        }
    }
    pi_scale_kernel<<<(N + 255) / 256, 256, 0, stream>>>(bufA, nsq + ITERS, out);
}